// Round 1
// baseline (234.986 us; speedup 1.0000x reference)
//
#include <hip/hip_runtime.h>

#define NB 4
#define NL 1024
#define NH 8
#define ND 64
#define NBH 32   // NB*NH

typedef __attribute__((ext_vector_type(8))) short bhalf8;
typedef __attribute__((ext_vector_type(4))) float f32x4;

static __device__ inline unsigned short f2bf(float f) {
    union { float f; unsigned u; } x; x.f = f;
    unsigned r = x.u + 0x7FFFu + ((x.u >> 16) & 1u);   // round-nearest-even
    return (unsigned short)(r >> 16);
}

// ---------------------------------------------------------------------------
// Kernel 1: L2-normalize q (with 1/T folded in) and k; transpose [B,L,H,D] ->
// head-major [B,H,L,D] bf16 in workspace. One wave per (b,l,h) row (D=64).
// ---------------------------------------------------------------------------
__global__ __launch_bounds__(256) void norm_qk_kernel(const float* __restrict__ q,
                                                      const float* __restrict__ k,
                                                      unsigned short* __restrict__ qn,
                                                      unsigned short* __restrict__ kn) {
    int wid  = threadIdx.x >> 6;
    int lane = threadIdx.x & 63;
    int r = blockIdx.x * 4 + wid;            // row over (b,l,h), 0..32767
    int b = r >> 13;                         // / (L*H)
    int l = (r >> 3) & (NL - 1);
    int h = r & (NH - 1);

    float qv = q[(size_t)r * ND + lane];
    float kv = k[(size_t)r * ND + lane];
    float qs = qv * qv, ks = kv * kv;
    #pragma unroll
    for (int m = 1; m < 64; m <<= 1) {
        qs += __shfl_xor(qs, m);
        ks += __shfl_xor(ks, m);
    }
    float qd = 1.0f / (fmaxf(sqrtf(qs), 1e-8f) * 8.0f);   // fold 1/TEMPERATURE
    float kd = 1.0f / fmaxf(sqrtf(ks), 1e-8f);

    size_t o = ((size_t)(b * NH + h) * NL + l) * ND + lane;
    qn[o] = f2bf(qv * qd);
    kn[o] = f2bf(kv * kd);
}

// ---------------------------------------------------------------------------
// Kernel 2: v [B,L,H,D] fp32 -> vt [B,H,D,L] bf16 via LDS tile transpose.
// Grid (NBH, NL/64), block 256. tile[65] pad -> conflict-free.
// ---------------------------------------------------------------------------
__global__ __launch_bounds__(256) void vtrans_kernel(const float* __restrict__ v,
                                                     unsigned short* __restrict__ vt) {
    __shared__ float tile[64 * 65];
    int bh = blockIdx.x;
    int b = bh >> 3, h = bh & 7;
    int l0 = blockIdx.y * 64;
    int wid = threadIdx.x >> 6, lane = threadIdx.x & 63;

    #pragma unroll
    for (int rr = 0; rr < 16; ++rr) {
        int row = rr * 4 + wid;
        float val = v[(((size_t)b * NL + l0 + row) * NH + h) * ND + lane];
        tile[lane * 65 + row] = val;         // bank = (lane+row)%32 pattern, 2-way max
    }
    __syncthreads();
    #pragma unroll
    for (int dd = 0; dd < 16; ++dd) {
        int d = dd * 4 + wid;
        vt[((size_t)(bh * ND + d)) * NL + l0 + lane] = f2bf(tile[d * 65 + lane]);
    }
}

// ---------------------------------------------------------------------------
// Kernel 3: fused cosine attention. Grid (NBH, 16), block 256 (4 waves).
// Each wave owns 16 query rows: pass 1 = softmax denominator (recompute-cheap
// QK via mfma_f32_16x16x32_bf16), pass 2 = recompute scores, write attn,
// LDS-transpose P (C-layout -> A-layout), accumulate PV.
// ---------------------------------------------------------------------------
__global__ __launch_bounds__(256) void attn_kernel(const unsigned short* __restrict__ qn,
                                                   const unsigned short* __restrict__ kn,
                                                   const unsigned short* __restrict__ vt,
                                                   float* __restrict__ outp,
                                                   float* __restrict__ attnp) {
    int bh   = blockIdx.x;                   // 0..31
    int wid  = threadIdx.x >> 6;
    int lane = threadIdx.x & 63;
    int c    = lane & 15;
    int quad = lane >> 4;
    int qt   = blockIdx.y * 4 + wid;         // 0..63
    int m0   = qt * 16;

    // P tile per wave: 16 rows x 32 cols bf16, row stride 40 (pad 8 -> 16B-aligned rows)
    __shared__ __align__(16) unsigned short ptile[4][16 * 40];
    unsigned short* myp = &ptile[wid][0];

    // A-frag of Q: lane holds A[m=c][k=quad*8+j]
    const unsigned short* qbase = qn + ((size_t)(bh * NL + m0 + c)) * ND + quad * 8;
    bhalf8 qa0 = *(const bhalf8*)(qbase);
    bhalf8 qa1 = *(const bhalf8*)(qbase + 32);

    const unsigned short* kbh = kn + (size_t)bh * NL * ND;

    // ---- pass 1: denominators ----
    float denom[4] = {0.f, 0.f, 0.f, 0.f};
    for (int jt = 0; jt < 64; ++jt) {
        const unsigned short* kb = kbh + ((size_t)(jt * 16 + c)) * ND + quad * 8;
        bhalf8 kf0 = *(const bhalf8*)(kb);
        bhalf8 kf1 = *(const bhalf8*)(kb + 32);
        f32x4 s = {0.f, 0.f, 0.f, 0.f};
        s = __builtin_amdgcn_mfma_f32_16x16x32_bf16(qa0, kf0, s, 0, 0, 0);
        s = __builtin_amdgcn_mfma_f32_16x16x32_bf16(qa1, kf1, s, 0, 0, 0);
        #pragma unroll
        for (int r = 0; r < 4; ++r) denom[r] += __expf(s[r]);
    }
    #pragma unroll
    for (int r = 0; r < 4; ++r) {
        float d = denom[r];
        d += __shfl_xor(d, 1);
        d += __shfl_xor(d, 2);
        d += __shfl_xor(d, 4);
        d += __shfl_xor(d, 8);               // reduce over the 16 col-lanes of this quad
        denom[r] = 1.0f / d;
    }

    // ---- pass 2: attn write + PV ----
    float* attnrow = attnp + ((size_t)(bh * NL + m0)) * NL;
    const unsigned short* vbh = vt + (size_t)bh * ND * NL;

    f32x4 o[4] = {{0.f,0.f,0.f,0.f},{0.f,0.f,0.f,0.f},{0.f,0.f,0.f,0.f},{0.f,0.f,0.f,0.f}};
    for (int j2 = 0; j2 < 32; ++j2) {
        int jb = j2 * 32;
        #pragma unroll
        for (int sub = 0; sub < 2; ++sub) {
            int j0 = jb + sub * 16;
            const unsigned short* kb = kbh + ((size_t)(j0 + c)) * ND + quad * 8;
            bhalf8 kf0 = *(const bhalf8*)(kb);
            bhalf8 kf1 = *(const bhalf8*)(kb + 32);
            f32x4 s = {0.f, 0.f, 0.f, 0.f};
            s = __builtin_amdgcn_mfma_f32_16x16x32_bf16(qa0, kf0, s, 0, 0, 0);
            s = __builtin_amdgcn_mfma_f32_16x16x32_bf16(qa1, kf1, s, 0, 0, 0);
            #pragma unroll
            for (int r = 0; r < 4; ++r) {
                float a = __expf(s[r]) * denom[r];
                attnrow[(size_t)(quad * 4 + r) * NL + j0 + c] = a;
                myp[(quad * 4 + r) * 40 + sub * 16 + c] = f2bf(a);
            }
        }
        // C-layout -> A-layout round trip (same-wave LDS, compiler inserts lgkmcnt)
        bhalf8 pa = *(const bhalf8*)(myp + c * 40 + quad * 8);
        #pragma unroll
        for (int nt = 0; nt < 4; ++nt) {
            const unsigned short* vb = vbh + (size_t)(nt * 16 + c) * NL + jb + quad * 8;
            bhalf8 vf = *(const bhalf8*)(vb);
            o[nt] = __builtin_amdgcn_mfma_f32_16x16x32_bf16(pa, vf, o[nt], 0, 0, 0);
        }
    }

    float* obase = outp + ((size_t)(bh * NL + m0)) * ND;
    #pragma unroll
    for (int nt = 0; nt < 4; ++nt) {
        #pragma unroll
        for (int r = 0; r < 4; ++r) {
            obase[(size_t)(quad * 4 + r) * ND + nt * 16 + c] = o[nt][r];
        }
    }
}

// ---------------------------------------------------------------------------
extern "C" void kernel_launch(void* const* d_in, const int* in_sizes, int n_in,
                              void* d_out, int out_size, void* d_ws, size_t ws_size,
                              hipStream_t stream) {
    const float* q = (const float*)d_in[0];
    const float* k = (const float*)d_in[1];
    const float* v = (const float*)d_in[2];

    float* outp  = (float*)d_out;                              // [B,H,L,D] = 2M fp32
    float* attnp = outp + (size_t)NB * NH * NL * ND;           // [B,H,L,L] = 33.5M fp32

    unsigned short* qn = (unsigned short*)d_ws;                // 2M bf16
    unsigned short* kn = qn + (size_t)NB * NH * NL * ND;       // 2M bf16
    unsigned short* vt = kn + (size_t)NB * NH * NL * ND;       // 2M bf16 (total 12 MB ws)

    norm_qk_kernel<<<(NB * NL * NH) / 4, 256, 0, stream>>>(q, k, qn, kn);
    vtrans_kernel<<<dim3(NBH, NL / 64), 256, 0, stream>>>(v, vt);
    attn_kernel<<<dim3(NBH, NL / 16 / 4), 256, 0, stream>>>(qn, kn, vt, outp, attnp);
}